// Round 12
// baseline (587.553 us; speedup 1.0000x reference)
//
#include <hip/hip_runtime.h>
#include <hip/hip_bf16.h>
#include <math.h>

#define SEQ 2048
#define DKH 64
#define NH 16
#define NEGV -10000.0f
#define LIST_CAP 160
// 0.125 (1/sqrt(dk)) * log2(e): scores stored pre-scaled for exp2 softmax.
// Kept-set and top-k selection are invariant under positive scaling.
#define SSCL 0.18033688f

typedef __attribute__((ext_vector_type(8))) short short8;
typedef __attribute__((ext_vector_type(4))) float f32x4;

__device__ __forceinline__ unsigned int f2k(float f) {
  unsigned int u = __float_as_uint(f);
  return (u & 0x80000000u) ? ~u : (u | 0x80000000u);
}
__device__ __forceinline__ float k2f(unsigned int k) {
  unsigned int u = (k & 0x80000000u) ? (k & 0x7FFFFFFFu) : ~k;
  return __uint_as_float(u);
}
__device__ __forceinline__ int lanecnt_lt(unsigned long long m) {
  return __builtin_amdgcn_mbcnt_hi((unsigned int)(m >> 32),
         __builtin_amdgcn_mbcnt_lo((unsigned int)m, 0));
}
__device__ __forceinline__ void split_hl(float x, unsigned short* h, unsigned short* l) {
  unsigned int u = __float_as_uint(x);
  *h = (unsigned short)(u >> 16);
  float hf = __uint_as_float(u & 0xffff0000u);
  *l = (unsigned short)(__float_as_uint(x - hf) >> 16);
}
__device__ __forceinline__ void glds16(const unsigned short* g, unsigned short* l) {
  __builtin_amdgcn_global_load_lds(
      (const __attribute__((address_space(1))) unsigned int*)g,
      (__attribute__((address_space(3))) unsigned int*)l, 16, 0, 0);
}
// LDS-only barrier: waits own LDS ops, does NOT drain vmcnt.
__device__ __forceinline__ void lds_barrier() {
  asm volatile("s_waitcnt lgkmcnt(0)" ::: "memory");
  __builtin_amdgcn_s_barrier();
  asm volatile("" ::: "memory");
}

// ---------------------------------------------------------------------------
// fp32 -> [hi(1024) | lo(1024)] bf16 planes, row-major M x 2048 ushort.
// ---------------------------------------------------------------------------
__global__ __launch_bounds__(256)
void conv_xhl(const float* __restrict__ X, unsigned short* __restrict__ O)
{
  int idx = blockIdx.x * 256 + threadIdx.x;   // one thread per 4 elements
  int m = idx >> 8;
  int c = (idx & 255) * 4;
  float4 v = *(const float4*)(X + (size_t)m * 1024 + c);
  float xs[4] = {v.x, v.y, v.z, v.w};
  ushort4 h, l;
  unsigned short hh[4], ll[4];
#pragma unroll
  for (int q = 0; q < 4; q++) split_hl(xs[q], &hh[q], &ll[q]);
  h.x=hh[0]; h.y=hh[1]; h.z=hh[2]; h.w=hh[3];
  l.x=ll[0]; l.y=ll[1]; l.z=ll[2]; l.w=ll[3];
  *(ushort4*)(O + (size_t)m * 2048 + c) = h;
  *(ushort4*)(O + (size_t)m * 2048 + 1024 + c) = l;
}

// Same for weights (1024 x 1024 fp32 -> 1024 x 2048 hl).
__global__ __launch_bounds__(256)
void conv_whl(const float* __restrict__ W, unsigned short* __restrict__ O)
{
  int idx = blockIdx.x * 256 + threadIdx.x;
  int n = idx >> 8;
  int c = (idx & 255) * 4;
  float4 v = *(const float4*)(W + (size_t)n * 1024 + c);
  float xs[4] = {v.x, v.y, v.z, v.w};
  ushort4 h, l;
  unsigned short hh[4], ll[4];
#pragma unroll
  for (int q = 0; q < 4; q++) split_hl(xs[q], &hh[q], &ll[q]);
  h.x=hh[0]; h.y=hh[1]; h.z=hh[2]; h.w=hh[3];
  l.x=ll[0]; l.y=ll[1]; l.z=ll[2]; l.w=ll[3];
  *(ushort4*)(O + (size_t)n * 2048 + c) = h;
  *(ushort4*)(O + (size_t)n * 2048 + 1024 + c) = l;
}

// ---------------------------------------------------------------------------
// Split-bf16 MFMA GEMM, FUSED 3-TERM K-LOOP (round 11, -100 us) + XCD-AFFINE
// SWIZZLE (round 12). C[m,n] = sum_c X[m,c]*W[n,c] + bias[n] via
// Xhi*Whi + Xlo*Whi + Xhi*Wlo, one K in [0,1024) loop staging all 4 planes:
// 16 steps, 32 barriers, 48 MFMA/wave/step.
// ROUND-12: swz = (bid&7)*64 + (bid>>3) (bijective, 512=8x64). XCD x owns
// mb in {4x..4x+3} x all nb -> per-K-step working set 4x32KB A + 16x16KB B
// = 384KB, L2-resident. Linear ids round-robin same-mb blocks over all 8
// XCDs -> every XCD re-fetches every A-slice (~160 MB/GEMM from HBM);
// affine cuts to ~48 MB. Same mechanism as attn's round-7 swizzle
// (FETCH 139->34 MB, -80 us). Round-4's swizzle test was bundled with
// BK=128 and unattributable — this is the isolated test.
// (Failed levers, do not retry: BK=128 r4, source-dbuf r9, 64x64 tile r10.)
// Tile 128(M) x 64(N), BK=64, 256 thr, grid 512.
// Epilogue modes: 0 fp32 [m][n]; 1 bhsd hl (q,k); 2 bhsd fp32 (v).
// ---------------------------------------------------------------------------
__global__ __launch_bounds__(256)
void gemm_mfma(const unsigned short* __restrict__ A,
               const unsigned short* __restrict__ Bw,
               const float* __restrict__ bias,
               float* __restrict__ outF,
               unsigned short* __restrict__ outHL,
               float* __restrict__ outBH,
               int mode)
{
  __shared__ unsigned short AsH[128 * 64];   // 16 KB
  __shared__ unsigned short AsL[128 * 64];   // 16 KB
  __shared__ unsigned short BsH[64 * 64];    // 8 KB
  __shared__ unsigned short BsL[64 * 64];    // 8 KB
  const int t = threadIdx.x, lane = t & 63, w = t >> 6;
  const int bid = blockIdx.x;
  const int swz = (bid & 7) * 64 + (bid >> 3);   // XCD-affine, bijective
  const int nb = swz & 15, mb = swz >> 4;
  const int m0 = mb * 128, n0 = nb * 64;
  const int am = lane & 15, aq = lane >> 4;
  const int wr = w >> 1, wc = w & 1;
  const int srow = lane >> 3;
  const int scol = (lane & 7) * 8;

  f32x4 acc[4][2];
#pragma unroll
  for (int mt = 0; mt < 4; mt++)
#pragma unroll
    for (int nt = 0; nt < 2; nt++) acc[mt][nt] = (f32x4){0.f, 0.f, 0.f, 0.f};

  for (int kx = 0; kx < 1024; kx += 64) {
    __syncthreads();
#pragma unroll
    for (int ch = 0; ch < 4; ch++) {                 // A: 128 rows, hi+lo planes
      int row = w * 32 + ch * 8 + srow;
      const unsigned short* ap = A + (size_t)(m0 + row) * 2048 + kx + scol;
      glds16(ap,        &AsH[(w * 32 + ch * 8) * 64 + lane * 8]);
      glds16(ap + 1024, &AsL[(w * 32 + ch * 8) * 64 + lane * 8]);
    }
#pragma unroll
    for (int ch = 0; ch < 2; ch++) {                 // B: 64 rows, hi+lo planes
      int row = w * 16 + ch * 8 + srow;
      const unsigned short* bp = Bw + (size_t)(n0 + row) * 2048 + kx + scol;
      glds16(bp,        &BsH[(w * 16 + ch * 8) * 64 + lane * 8]);
      glds16(bp + 1024, &BsL[(w * 16 + ch * 8) * 64 + lane * 8]);
    }
    __syncthreads();

#pragma unroll
    for (int kk = 0; kk < 2; kk++) {
      short8 ah[4], al[4], bh[2], bl[2];
#pragma unroll
      for (int mt = 0; mt < 4; mt++) {
        const int ro = (wr * 64 + mt * 16 + am) * 64 + kk * 32 + aq * 8;
        ah[mt] = *(const short8*)&AsH[ro];
        al[mt] = *(const short8*)&AsL[ro];
      }
#pragma unroll
      for (int nt = 0; nt < 2; nt++) {
        const int ro = (wc * 32 + nt * 16 + am) * 64 + kk * 32 + aq * 8;
        bh[nt] = *(const short8*)&BsH[ro];
        bl[nt] = *(const short8*)&BsL[ro];
      }
#pragma unroll
      for (int mt = 0; mt < 4; mt++)
#pragma unroll
        for (int nt = 0; nt < 2; nt++) {
          acc[mt][nt] = __builtin_amdgcn_mfma_f32_16x16x32_bf16(ah[mt], bh[nt], acc[mt][nt], 0, 0, 0);
          acc[mt][nt] = __builtin_amdgcn_mfma_f32_16x16x32_bf16(al[mt], bh[nt], acc[mt][nt], 0, 0, 0);
          acc[mt][nt] = __builtin_amdgcn_mfma_f32_16x16x32_bf16(ah[mt], bl[nt], acc[mt][nt], 0, 0, 0);
        }
    }
  }

#pragma unroll
  for (int mt = 0; mt < 4; mt++)
#pragma unroll
    for (int nt = 0; nt < 2; nt++)
#pragma unroll
      for (int reg = 0; reg < 4; reg++) {
        const int gm = m0 + wr * 64 + mt * 16 + aq * 4 + reg;
        const int gn = n0 + wc * 32 + nt * 16 + am;
        float val = acc[mt][nt][reg] + bias[gn];
        if (mode == 0) {
          outF[(size_t)gm * 1024 + gn] = val;
        } else {
          const int bb = gm >> 11, s = gm & 2047, h2 = gn >> 6, d = gn & 63;
          const size_t row = ((size_t)(bb * NH + h2)) * SEQ + s;
          if (mode == 2) {
            outBH[row * DKH + d] = val;
          } else {
            unsigned short h, l;
            split_hl(val, &h, &l);
            outHL[row * 128 + d] = h;
            outHL[row * 128 + 64 + d] = l;
          }
        }
      }
}

// ---------------------------------------------------------------------------
// Attention: split-bf16 MFMA QK^T + exact causal top-64 + sparse PV.
// ROUND-7 CONFIG (proven ~346-355 us across 4 rounds). Occupancy levers
// closed (round 8: same 68% at 3- and 4-block LDS). Features: XCD-affine
// block map (d&7 = XCD owns 4 heads -> K/V L2-resident, FETCH 139->30 MB),
// raw-float scores in regs, LDS-masked causal (tail fill), exp2 softmax,
// lgkm-only barriers, scores staged in TWO 1024-key halves, full 16-reg
// B-fragment preload. Register liveness rule (round-5): PV pipeline state
// strictly inside the sparse arm where sc[32] are dead.
// ---------------------------------------------------------------------------
struct AttnSmem {
  float scores[8][1024];                // 32 KB, staged half of the row
  float2 pl[8][LIST_CAP + 32];          // 12 KB packed (p, j) list + 32 pad
  float cand[8][64];                    // 2 KB
};

// absorb one staged half (16 chunks) into sc[U0..U0+15]; U0 literal so
// every sc[] index is compile-time (else -> scratch). Causal mask already
// in LDS (phase-1 writes NEGV beyond each row's bound + tail fill).
#define LOAD_CHUNKS(U0)                                                      \
  {                                                                          \
    _Pragma("unroll")                                                        \
    for (int ul = 0; ul < 16; ul++) {                                        \
      const int u = (U0) + ul;                                               \
      if ((u << 6) <= i) {                                                   \
        float vm = sm.scores[r][(ul << 6) + lane];                           \
        float va = (vm > -5000.0f) ? vm : 0.0f;                              \
        vmax = fmaxf(vmax, vm);                                              \
        s1 += va;                                                            \
        s2 = fmaf(va, va, s2);                                               \
        sc[u] = vm;                                                          \
      }                                                                      \
    }                                                                        \
  }

__global__ __launch_bounds__(512, 6)
void attn_topk(const unsigned short* __restrict__ qhl, const unsigned short* __restrict__ khl,
               const float* __restrict__ vp, unsigned short* __restrict__ aohl)
{
  __shared__ AttnSmem sm;
  const int t    = threadIdx.x;
  const int lane = t & 63;
  const int w    = t >> 6;            // 0..7
  // XCD-affine bijective map: XCD x = d&7 owns heads {4x..4x+3}; heavy rows
  // (large i0) dispatch first within each XCD.
  const int d    = blockIdx.x;
  const int s5   = d >> 3;
  const int bh   = (d & 7) * 4 + (s5 & 3);
  const int rb   = 255 - (s5 >> 2);
  const int i0   = rb * 8;
  const unsigned short* qb = qhl + (size_t)bh * SEQ * 128;
  const unsigned short* kb = khl + (size_t)bh * SEQ * 128;
  const float* vbase = vp + (size_t)bh * SEQ * DKH;

  // ---- phase 1/absorb interleaved per 1024-key half ----
  const int am   = lane & 15;
  const int aq   = lane >> 4;
  const int dofs = aq * 8;
  const int r = w;
  const int i = i0 + w;

  short8 a_hi[2], a_lo[2];
#pragma unroll
  for (int c = 0; c < 2; c++) {
    size_t off = (size_t)(i0 + am) * 128 + c * 32 + dofs;  // rows 8..15 over-read -> next buffer, discarded
    a_hi[c] = *(const short8*)(qb + off);
    a_lo[c] = *(const short8*)(qb + off + 64);
  }

  const int T = (i0 >> 4) + 1;

  // compute tiles [s*64, min(T, s*64+64)) of QK^T into sm.scores (half-local
  // cols), then NEGV-fill the tail up to the 64-chunk boundary so phase-2
  // reads need no per-lane masking. Full 16-reg fragment preload per tile.
  auto phase1_stage = [&](int s) {
    const int tlo = s << 6;
    const int thi = (T < tlo + 64) ? T : (tlo + 64);
    for (int tt = tlo + w; tt < thi; tt += 8) {
      short8 b_hi[2], b_lo[2];
#pragma unroll
      for (int c = 0; c < 2; c++) {
        size_t off = (size_t)(tt * 16 + am) * 128 + c * 32 + dofs;
        b_hi[c] = *(const short8*)(kb + off);
        b_lo[c] = *(const short8*)(kb + off + 64);
      }
      f32x4 C = {0.0f, 0.0f, 0.0f, 0.0f};
#pragma unroll
      for (int c = 0; c < 2; c++) {
        C = __builtin_amdgcn_mfma_f32_16x16x32_bf16(a_hi[c], b_hi[c], C, 0, 0, 0);
        C = __builtin_amdgcn_mfma_f32_16x16x32_bf16(a_lo[c], b_hi[c], C, 0, 0, 0);
        C = __builtin_amdgcn_mfma_f32_16x16x32_bf16(a_hi[c], b_lo[c], C, 0, 0, 0);
      }
      if (aq < 2) {
        const int j = tt * 16 + am;
        const int jc = j - (s << 10);
#pragma unroll
        for (int reg = 0; reg < 4; reg++) {
          const int rr = aq * 4 + reg;
          sm.scores[rr][jc] = (j <= i0 + rr) ? C[reg] * SSCL : NEGV;
        }
      }
    }
    // tail fill: [T*16, next 64-boundary past i0+7), clipped to this stage
    const int fs = T << 4;
    const int fe = (((i0 + 7) >> 6) + 1) << 6;
    const int slo = s << 10, shi = slo + 1024;
    const int lo = fs > slo ? fs : slo;
    const int hi = fe < shi ? fe : shi;
    for (int j = lo + lane; j < hi; j += 64) sm.scores[r][j - slo] = NEGV;
  };

  float sc[32];
#pragma unroll
  for (int u = 0; u < 32; u++) sc[u] = NEGV;
  float vmax = NEGV, s1 = 0.0f, s2 = 0.0f;

  phase1_stage(0);
  lds_barrier();
  LOAD_CHUNKS(0)
  if (i0 >= 1024) {                    // block-uniform: second half exists
    lds_barrier();                     // all waves done reading half 0
    phase1_stage(1);
    lds_barrier();
    LOAD_CHUNKS(16)
  }

  // ---- selection: stats reduction + probe-seeded exact bisection ----
#pragma unroll
  for (int off = 32; off; off >>= 1) {
    vmax = fmaxf(vmax, __shfl_xor(vmax, off));
    s1 += __shfl_xor(s1, off);
    s2 += __shfl_xor(s2, off);
  }

  auto countge = [&](float th) -> int {
    int cnt = 0;
#pragma unroll
    for (int u = 0; u < 32; u++)
      if ((u << 6) <= i)
        cnt += __popcll(__ballot(sc[u] >= th));
    return cnt;
  };

  float vk;
  if (i + 1 <= 64) {
    vk = NEGV;                         // <=64 valid: keep all
  } else {
    const float n1  = (float)(i + 1);
    const float mu  = s1 / n1;
    const float sig = sqrtf(fmaxf(s2 / n1 - mu * mu, 0.0f));
    // inverse-normal probe targeting count ~128 (Hastings approx)
    const float qf = fminf(0.45f, 128.0f / n1);
    const float tq = sqrtf(-2.0f * __logf(qf));
    const float zq = tq - (2.30753f + 0.27061f * tq) /
                          (1.0f + tq * (0.99229f + 0.04481f * tq));
    unsigned int ka, kb2;
    int ca, cb;
    {
      const float t1 = mu + zq * sig;
      const int c1 = countge(t1);
      if (c1 >= 64) { ka = f2k(t1); ca = c1; kb2 = f2k(vmax) + 1u; cb = 0; }
      else {
        const float t2 = mu + (zq - 0.85f) * sig;
        const int c2 = countge(t2);
        if (c2 >= 64) { ka = f2k(t2); ca = c2; kb2 = f2k(t1); cb = c1; }
        else { ka = f2k(-5000.0f); ca = i + 1; kb2 = f2k(t2); cb = c2; }
      }
    }
    int guard = 0;
    while (kb2 - ka > 1u && (ca - cb) > 56 && guard < 64) {
      guard++;
      float fm = 0.5f * (k2f(ka) + k2f(kb2));
      unsigned int km = f2k(fm);
      if (km <= ka || km >= kb2) km = ka + ((kb2 - ka) >> 1);
      const int cnt = countge(k2f(km));
      if (cnt >= 64) { ka = km; ca = cnt; } else { kb2 = km; cb = cnt; }
    }
    if (kb2 - ka == 1u || (ca - cb) > 64) {
      vk = k2f(ka);                    // interval collapsed (dups) -> exact
    } else {
      const float fka = k2f(ka), fkb = k2f(kb2);
      int cbase = 0;
#pragma unroll
      for (int u = 0; u < 32; u++) {
        if ((u << 6) <= i) {
          float kx = sc[u];
          bool in = (kx >= fka && kx < fkb);
          unsigned long long mask = __ballot(in);
          if (in) sm.cand[w][cbase + lanecnt_lt(mask)] = kx;
          cbase += __popcll(mask);
        }
      }
      const int nc = cbase;            // <= 64 on this path
      float cv = (lane < nc) ? sm.cand[w][lane] : -3.4e38f;
      for (int ks = 2; ks <= 64; ks <<= 1) {
        for (int j2 = ks >> 1; j2 > 0; j2 >>= 1) {
          float other = __shfl_xor(cv, j2);
          bool up    = ((lane & ks) == 0);
          bool lower = ((lane & j2) == 0);
          float mn = fminf(cv, other), mx = fmaxf(cv, other);
          cv = (up == lower) ? mn : mx;
        }
      }
      int need = 64 - cb;
      vk = __shfl(cv, 64 - need);
    }
  }

  // softmax + packed (p, j) kept list (scores pre-scaled by log2e -> exp2f)
  float z = 0.0f;
  int base = 0;
#pragma unroll
  for (int u = 0; u < 32; u++) {
    if ((u << 6) <= i) {
      const int j = (u << 6) + lane;
      float sv = sc[u];
      float p = (sv >= vk) ? exp2f(sv - vmax) : 0.0f;  // NEG entries -> exactly 0
      z += p;
      unsigned long long mask = __ballot(p > 0.0f);
      if (p > 0.0f) {
        int pos = base + lanecnt_lt(mask);
        if (pos < LIST_CAP) {
          float2 e; e.x = p; e.y = __uint_as_float((unsigned int)j);
          sm.pl[r][pos] = e;
        }
      }
      base += __popcll(mask);
    }
  }
#pragma unroll
  for (int off = 32; off; off >>= 1) z += __shfl_xor(z, off);
  const float rz = 1.0f / z;

  // ---- PV ----
  const float* vb2 = vbase + lane;
  float acc = 0.0f;
  if (base <= LIST_CAP) {
    // sparse: two-deep pipelined batches of 8. sc[] dead on this arm —
    // pipeline state reuses their registers (do not hoist out of this block).
    if (lane < 32) {                   // 32 zero-pads cover all refills:
      float2 e; e.x = 0.0f; e.y = __uint_as_float(0u);   // max idx = base+30
      sm.pl[r][base + lane] = e;
    }
    float2 curA[8], curB[8];
    float vvA[8], vvB[8];
#pragma unroll
    for (int s = 0; s < 8; s++) curA[s] = sm.pl[r][s];
#pragma unroll
    for (int s = 0; s < 8; s++) curB[s] = sm.pl[r][8 + s];
#pragma unroll
    for (int s = 0; s < 8; s++)
      vvA[s] = vb2[(size_t)(__float_as_uint(curA[s].y) << 6)];
#pragma unroll
    for (int s = 0; s < 8; s++)
      vvB[s] = vb2[(size_t)(__float_as_uint(curB[s].y) << 6)];

    const int nb2 = (base + 7) >> 3;
    for (int b = 0; b < nb2; b += 2) {
      // consume A (batch b), refill A with batch b+2
#pragma unroll
      for (int s = 0; s < 8; s++) acc = fmaf(curA[s].x, vvA[s], acc);
      const int ia = (b + 2) * 8;
#pragma unroll
      for (int s = 0; s < 8; s++) curA[s] = sm.pl[r][ia + s];
#pragma unroll
      for (int s = 0; s < 8; s++)
        vvA[s] = vb2[(size_t)(__float_as_uint(curA[s].y) << 6)];
      // consume B (batch b+1), refill B with batch b+3
#pragma unroll
      for (int s = 0; s < 8; s++) acc = fmaf(curB[s].x, vvB[s], acc);
      const int ib = (b + 3) * 8;
#pragma unroll
      for (int s = 0; s < 8; s++) curB[s] = sm.pl[r][ib + s];
#pragma unroll
      for (int s = 0; s < 8; s++)
        vvB[s] = vb2[(size_t)(__float_as_uint(curB[s].y) << 6)];
    }
  } else {                             // ties pathology: dense from registers
#pragma unroll
    for (int u = 0; u < 32; u++) {
      if ((u << 6) <= i) {
        float svu = sc[u];             // static index: sc stays in VGPRs
        for (int l2 = 0; l2 < 64; l2++) {
          const int jx = (u << 6) + l2;
          if (jx > i) break;
          float sv = __shfl(svu, l2);
          float p = (sv >= vk) ? exp2f(sv - vmax) : 0.0f;
          acc = fmaf(p, vb2[(size_t)((unsigned int)jx << 6)], acc);
        }
      }
    }
  }

  // epilogue: write ao as hl planes (row-major M x 2048) for the final GEMM
  const int bb = bh >> 4, hh = bh & 15;
  float val = acc * rz;
  unsigned short h, l;
  split_hl(val, &h, &l);
  const size_t arow = (size_t)(bb * SEQ + i) * 2048;
  aohl[arow + hh * 64 + lane] = h;
  aohl[arow + 1024 + hh * 64 + lane] = l;
}

// ---------------------------------------------------------------------------
extern "C" void kernel_launch(void* const* d_in, const int* in_sizes, int n_in,
                              void* d_out, int out_size, void* d_ws, size_t ws_size,
                              hipStream_t stream)
{
  const float* query = (const float*)d_in[0];
  const float* key   = (const float*)d_in[1];
  const float* value = (const float*)d_in[2];
  const float* Wq    = (const float*)d_in[3];
  const float* bq    = (const float*)d_in[4];
  const float* Wk    = (const float*)d_in[5];
  const float* bk    = (const float*)d_in[6];
  const float* Wv    = (const float*)d_in[7];
  const float* bv    = (const float*)d_in[8];
  const float* Wo    = (const float*)d_in[9];
  const float* bo    = (const float*)d_in[10];

  // ws (54.5 MB): xhl(16) | whl(4) | qhl(16) | khl(16). V fp32 lives in d_out
  // (scratch until the final GEMM overwrites it).
  unsigned short* xhl = (unsigned short*)d_ws;            // 4096 x 2048
  unsigned short* whl = xhl + (size_t)4096 * 2048;        // 1024 x 2048
  unsigned short* qhl = whl + (size_t)1024 * 2048;        // 65536 x 128 (bhsd hl)
  unsigned short* khl = qhl + (size_t)65536 * 128;
  float* vpf = (float*)d_out;                             // 65536 x 64 fp32 (bhsd)

  hipLaunchKernelGGL(conv_xhl, dim3(4096), dim3(256), 0, stream, query, xhl);
  hipLaunchKernelGGL(conv_whl, dim3(1024), dim3(256), 0, stream, Wq, whl);
  hipLaunchKernelGGL(gemm_mfma, dim3(512), dim3(256), 0, stream, xhl, whl, bq,
                     (float*)nullptr, qhl, (float*)nullptr, 1);
  hipLaunchKernelGGL(conv_xhl, dim3(4096), dim3(256), 0, stream, key, xhl);
  hipLaunchKernelGGL(conv_whl, dim3(1024), dim3(256), 0, stream, Wk, whl);
  hipLaunchKernelGGL(gemm_mfma, dim3(512), dim3(256), 0, stream, xhl, whl, bk,
                     (float*)nullptr, khl, (float*)nullptr, 1);
  hipLaunchKernelGGL(conv_xhl, dim3(4096), dim3(256), 0, stream, value, xhl);
  hipLaunchKernelGGL(conv_whl, dim3(1024), dim3(256), 0, stream, Wv, whl);
  hipLaunchKernelGGL(gemm_mfma, dim3(512), dim3(256), 0, stream, xhl, whl, bv,
                     (float*)nullptr, (unsigned short*)nullptr, vpf, 2);
  hipLaunchKernelGGL(attn_topk, dim3(8192), dim3(512), 0, stream, qhl, khl, vpf, xhl);
  hipLaunchKernelGGL(conv_whl, dim3(1024), dim3(256), 0, stream, Wo, whl);
  hipLaunchKernelGGL(gemm_mfma, dim3(512), dim3(256), 0, stream, xhl, whl, bo,
                     (float*)d_out, (unsigned short*)nullptr, (float*)nullptr, 0);
}

// Round 13
// 577.544 us; speedup vs baseline: 1.0173x; 1.0173x over previous
//
#include <hip/hip_runtime.h>
#include <hip/hip_bf16.h>
#include <math.h>

#define SEQ 2048
#define DKH 64
#define NH 16
#define NEGV -10000.0f
#define LIST_CAP 160
// 0.125 (1/sqrt(dk)) * log2(e): scores stored pre-scaled for exp2 softmax.
// Kept-set and top-k selection are invariant under positive scaling.
#define SSCL 0.18033688f

typedef __attribute__((ext_vector_type(8))) short short8;
typedef __attribute__((ext_vector_type(4))) float f32x4;

__device__ __forceinline__ unsigned int f2k(float f) {
  unsigned int u = __float_as_uint(f);
  return (u & 0x80000000u) ? ~u : (u | 0x80000000u);
}
__device__ __forceinline__ float k2f(unsigned int k) {
  unsigned int u = (k & 0x80000000u) ? (k & 0x7FFFFFFFu) : ~k;
  return __uint_as_float(u);
}
__device__ __forceinline__ int lanecnt_lt(unsigned long long m) {
  return __builtin_amdgcn_mbcnt_hi((unsigned int)(m >> 32),
         __builtin_amdgcn_mbcnt_lo((unsigned int)m, 0));
}
__device__ __forceinline__ void split_hl(float x, unsigned short* h, unsigned short* l) {
  unsigned int u = __float_as_uint(x);
  *h = (unsigned short)(u >> 16);
  float hf = __uint_as_float(u & 0xffff0000u);
  *l = (unsigned short)(__float_as_uint(x - hf) >> 16);
}
__device__ __forceinline__ void glds16(const unsigned short* g, unsigned short* l) {
  __builtin_amdgcn_global_load_lds(
      (const __attribute__((address_space(1))) unsigned int*)g,
      (__attribute__((address_space(3))) unsigned int*)l, 16, 0, 0);
}
// LDS-only barrier: waits own LDS ops, does NOT drain vmcnt.
__device__ __forceinline__ void lds_barrier() {
  asm volatile("s_waitcnt lgkmcnt(0)" ::: "memory");
  __builtin_amdgcn_s_barrier();
  asm volatile("" ::: "memory");
}

// ---------------------------------------------------------------------------
// fp32 -> [hi(1024) | lo(1024)] bf16 planes, row-major M x 2048 ushort.
// ---------------------------------------------------------------------------
__global__ __launch_bounds__(256)
void conv_xhl(const float* __restrict__ X, unsigned short* __restrict__ O)
{
  int idx = blockIdx.x * 256 + threadIdx.x;   // one thread per 4 elements
  int m = idx >> 8;
  int c = (idx & 255) * 4;
  float4 v = *(const float4*)(X + (size_t)m * 1024 + c);
  float xs[4] = {v.x, v.y, v.z, v.w};
  ushort4 h, l;
  unsigned short hh[4], ll[4];
#pragma unroll
  for (int q = 0; q < 4; q++) split_hl(xs[q], &hh[q], &ll[q]);
  h.x=hh[0]; h.y=hh[1]; h.z=hh[2]; h.w=hh[3];
  l.x=ll[0]; l.y=ll[1]; l.z=ll[2]; l.w=ll[3];
  *(ushort4*)(O + (size_t)m * 2048 + c) = h;
  *(ushort4*)(O + (size_t)m * 2048 + 1024 + c) = l;
}

// Same for weights (1024 x 1024 fp32 -> 1024 x 2048 hl).
__global__ __launch_bounds__(256)
void conv_whl(const float* __restrict__ W, unsigned short* __restrict__ O)
{
  int idx = blockIdx.x * 256 + threadIdx.x;
  int n = idx >> 8;
  int c = (idx & 255) * 4;
  float4 v = *(const float4*)(W + (size_t)n * 1024 + c);
  float xs[4] = {v.x, v.y, v.z, v.w};
  ushort4 h, l;
  unsigned short hh[4], ll[4];
#pragma unroll
  for (int q = 0; q < 4; q++) split_hl(xs[q], &hh[q], &ll[q]);
  h.x=hh[0]; h.y=hh[1]; h.z=hh[2]; h.w=hh[3];
  l.x=ll[0]; l.y=ll[1]; l.z=ll[2]; l.w=ll[3];
  *(ushort4*)(O + (size_t)n * 2048 + c) = h;
  *(ushort4*)(O + (size_t)n * 2048 + 1024 + c) = l;
}

// ---------------------------------------------------------------------------
// Split-bf16 MFMA GEMM, FUSED 3-TERM K-LOOP (round 11, -100 us) +
// CONSUMER-ALIGNED XCD SWIZZLE (round 13).
// C[m,n] = sum_c X[m,c]*W[n,c] + bias[n] via Xhi*Whi + Xlo*Whi + Xhi*Wlo,
// one K in [0,1024) loop staging all 4 planes: 16 steps, 32 barriers,
// 48 MFMA/wave/step.
// ROUND-13 SWIZZLE: x=bid&7 (XCD), j=bid>>3; mb=(x>>2)*16+(j>>2),
// nb=(x&3)*4+(j&3). Bijective (512=8x64). Writes bh=(mb>>4)*16+nb satisfy
// bh>>2 == x: each XCD writes EXACTLY the 4 bh that attn's XCD-affine map
// reads on that XCD. Round-12's swizzle ((bid&7)*64+(bid>>3)) gave the same
// GEMM gain (-40 us chain) but scattered each head's q/k writes across all
// 8 XCDs' L2s — attn (byte-identical) slowed +40 us with FETCH 30->36 MB.
// Per-XCD K-step working set: A 512 KB + B 64 KB (L2-fits); HBM ~40 MB/GEMM.
// (Failed levers, do not retry: BK=128 r4, source-dbuf r9, 64x64 tile r10.)
// Tile 128(M) x 64(N), BK=64, 256 thr, grid 512.
// Epilogue modes: 0 fp32 [m][n]; 1 bhsd hl (q,k); 2 bhsd fp32 (v).
// ---------------------------------------------------------------------------
__global__ __launch_bounds__(256)
void gemm_mfma(const unsigned short* __restrict__ A,
               const unsigned short* __restrict__ Bw,
               const float* __restrict__ bias,
               float* __restrict__ outF,
               unsigned short* __restrict__ outHL,
               float* __restrict__ outBH,
               int mode)
{
  __shared__ unsigned short AsH[128 * 64];   // 16 KB
  __shared__ unsigned short AsL[128 * 64];   // 16 KB
  __shared__ unsigned short BsH[64 * 64];    // 8 KB
  __shared__ unsigned short BsL[64 * 64];    // 8 KB
  const int t = threadIdx.x, lane = t & 63, w = t >> 6;
  const int bid = blockIdx.x;
  const int x = bid & 7, j = bid >> 3;           // XCD, intra-XCD index
  const int mb = (x >> 2) * 16 + (j >> 2);       // consumer-aligned:
  const int nb = (x & 3) * 4 + (j & 3);          // XCD x writes bh 4x..4x+3
  const int m0 = mb * 128, n0 = nb * 64;
  const int am = lane & 15, aq = lane >> 4;
  const int wr = w >> 1, wc = w & 1;
  const int srow = lane >> 3;
  const int scol = (lane & 7) * 8;

  f32x4 acc[4][2];
#pragma unroll
  for (int mt = 0; mt < 4; mt++)
#pragma unroll
    for (int nt = 0; nt < 2; nt++) acc[mt][nt] = (f32x4){0.f, 0.f, 0.f, 0.f};

  for (int kx = 0; kx < 1024; kx += 64) {
    __syncthreads();
#pragma unroll
    for (int ch = 0; ch < 4; ch++) {                 // A: 128 rows, hi+lo planes
      int row = w * 32 + ch * 8 + srow;
      const unsigned short* ap = A + (size_t)(m0 + row) * 2048 + kx + scol;
      glds16(ap,        &AsH[(w * 32 + ch * 8) * 64 + lane * 8]);
      glds16(ap + 1024, &AsL[(w * 32 + ch * 8) * 64 + lane * 8]);
    }
#pragma unroll
    for (int ch = 0; ch < 2; ch++) {                 // B: 64 rows, hi+lo planes
      int row = w * 16 + ch * 8 + srow;
      const unsigned short* bp = Bw + (size_t)(n0 + row) * 2048 + kx + scol;
      glds16(bp,        &BsH[(w * 16 + ch * 8) * 64 + lane * 8]);
      glds16(bp + 1024, &BsL[(w * 16 + ch * 8) * 64 + lane * 8]);
    }
    __syncthreads();

#pragma unroll
    for (int kk = 0; kk < 2; kk++) {
      short8 ah[4], al[4], bh[2], bl[2];
#pragma unroll
      for (int mt = 0; mt < 4; mt++) {
        const int ro = (wr * 64 + mt * 16 + am) * 64 + kk * 32 + aq * 8;
        ah[mt] = *(const short8*)&AsH[ro];
        al[mt] = *(const short8*)&AsL[ro];
      }
#pragma unroll
      for (int nt = 0; nt < 2; nt++) {
        const int ro = (wc * 32 + nt * 16 + am) * 64 + kk * 32 + aq * 8;
        bh[nt] = *(const short8*)&BsH[ro];
        bl[nt] = *(const short8*)&BsL[ro];
      }
#pragma unroll
      for (int mt = 0; mt < 4; mt++)
#pragma unroll
        for (int nt = 0; nt < 2; nt++) {
          acc[mt][nt] = __builtin_amdgcn_mfma_f32_16x16x32_bf16(ah[mt], bh[nt], acc[mt][nt], 0, 0, 0);
          acc[mt][nt] = __builtin_amdgcn_mfma_f32_16x16x32_bf16(al[mt], bh[nt], acc[mt][nt], 0, 0, 0);
          acc[mt][nt] = __builtin_amdgcn_mfma_f32_16x16x32_bf16(ah[mt], bl[nt], acc[mt][nt], 0, 0, 0);
        }
    }
  }

#pragma unroll
  for (int mt = 0; mt < 4; mt++)
#pragma unroll
    for (int nt = 0; nt < 2; nt++)
#pragma unroll
      for (int reg = 0; reg < 4; reg++) {
        const int gm = m0 + wr * 64 + mt * 16 + aq * 4 + reg;
        const int gn = n0 + wc * 32 + nt * 16 + am;
        float val = acc[mt][nt][reg] + bias[gn];
        if (mode == 0) {
          outF[(size_t)gm * 1024 + gn] = val;
        } else {
          const int bb = gm >> 11, s = gm & 2047, h2 = gn >> 6, d = gn & 63;
          const size_t row = ((size_t)(bb * NH + h2)) * SEQ + s;
          if (mode == 2) {
            outBH[row * DKH + d] = val;
          } else {
            unsigned short h, l;
            split_hl(val, &h, &l);
            outHL[row * 128 + d] = h;
            outHL[row * 128 + 64 + d] = l;
          }
        }
      }
}

// ---------------------------------------------------------------------------
// Attention: split-bf16 MFMA QK^T + exact causal top-64 + sparse PV.
// ROUND-7 CONFIG (proven ~346-355 us, rounds 7/9/10/11). Occupancy levers
// closed (round 8: same 68% at 3- and 4-block LDS). Features: XCD-affine
// block map (d&7 = XCD owns 4 heads -> K/V L2-resident, FETCH 139->30 MB),
// raw-float scores in regs, LDS-masked causal (tail fill), exp2 softmax,
// lgkm-only barriers, scores staged in TWO 1024-key halves, full 16-reg
// B-fragment preload. Register liveness rule (round-5): PV pipeline state
// strictly inside the sparse arm where sc[32] are dead.
// ---------------------------------------------------------------------------
struct AttnSmem {
  float scores[8][1024];                // 32 KB, staged half of the row
  float2 pl[8][LIST_CAP + 32];          // 12 KB packed (p, j) list + 32 pad
  float cand[8][64];                    // 2 KB
};

// absorb one staged half (16 chunks) into sc[U0..U0+15]; U0 literal so
// every sc[] index is compile-time (else -> scratch). Causal mask already
// in LDS (phase-1 writes NEGV beyond each row's bound + tail fill).
#define LOAD_CHUNKS(U0)                                                      \
  {                                                                          \
    _Pragma("unroll")                                                        \
    for (int ul = 0; ul < 16; ul++) {                                        \
      const int u = (U0) + ul;                                               \
      if ((u << 6) <= i) {                                                   \
        float vm = sm.scores[r][(ul << 6) + lane];                           \
        float va = (vm > -5000.0f) ? vm : 0.0f;                              \
        vmax = fmaxf(vmax, vm);                                              \
        s1 += va;                                                            \
        s2 = fmaf(va, va, s2);                                               \
        sc[u] = vm;                                                          \
      }                                                                      \
    }                                                                        \
  }

__global__ __launch_bounds__(512, 6)
void attn_topk(const unsigned short* __restrict__ qhl, const unsigned short* __restrict__ khl,
               const float* __restrict__ vp, unsigned short* __restrict__ aohl)
{
  __shared__ AttnSmem sm;
  const int t    = threadIdx.x;
  const int lane = t & 63;
  const int w    = t >> 6;            // 0..7
  // XCD-affine bijective map: XCD x = d&7 owns heads {4x..4x+3}; heavy rows
  // (large i0) dispatch first within each XCD.
  const int d    = blockIdx.x;
  const int s5   = d >> 3;
  const int bh   = (d & 7) * 4 + (s5 & 3);
  const int rb   = 255 - (s5 >> 2);
  const int i0   = rb * 8;
  const unsigned short* qb = qhl + (size_t)bh * SEQ * 128;
  const unsigned short* kb = khl + (size_t)bh * SEQ * 128;
  const float* vbase = vp + (size_t)bh * SEQ * DKH;

  // ---- phase 1/absorb interleaved per 1024-key half ----
  const int am   = lane & 15;
  const int aq   = lane >> 4;
  const int dofs = aq * 8;
  const int r = w;
  const int i = i0 + w;

  short8 a_hi[2], a_lo[2];
#pragma unroll
  for (int c = 0; c < 2; c++) {
    size_t off = (size_t)(i0 + am) * 128 + c * 32 + dofs;  // rows 8..15 over-read -> next buffer, discarded
    a_hi[c] = *(const short8*)(qb + off);
    a_lo[c] = *(const short8*)(qb + off + 64);
  }

  const int T = (i0 >> 4) + 1;

  // compute tiles [s*64, min(T, s*64+64)) of QK^T into sm.scores (half-local
  // cols), then NEGV-fill the tail up to the 64-chunk boundary so phase-2
  // reads need no per-lane masking. Full 16-reg fragment preload per tile.
  auto phase1_stage = [&](int s) {
    const int tlo = s << 6;
    const int thi = (T < tlo + 64) ? T : (tlo + 64);
    for (int tt = tlo + w; tt < thi; tt += 8) {
      short8 b_hi[2], b_lo[2];
#pragma unroll
      for (int c = 0; c < 2; c++) {
        size_t off = (size_t)(tt * 16 + am) * 128 + c * 32 + dofs;
        b_hi[c] = *(const short8*)(kb + off);
        b_lo[c] = *(const short8*)(kb + off + 64);
      }
      f32x4 C = {0.0f, 0.0f, 0.0f, 0.0f};
#pragma unroll
      for (int c = 0; c < 2; c++) {
        C = __builtin_amdgcn_mfma_f32_16x16x32_bf16(a_hi[c], b_hi[c], C, 0, 0, 0);
        C = __builtin_amdgcn_mfma_f32_16x16x32_bf16(a_lo[c], b_hi[c], C, 0, 0, 0);
        C = __builtin_amdgcn_mfma_f32_16x16x32_bf16(a_hi[c], b_lo[c], C, 0, 0, 0);
      }
      if (aq < 2) {
        const int j = tt * 16 + am;
        const int jc = j - (s << 10);
#pragma unroll
        for (int reg = 0; reg < 4; reg++) {
          const int rr = aq * 4 + reg;
          sm.scores[rr][jc] = (j <= i0 + rr) ? C[reg] * SSCL : NEGV;
        }
      }
    }
    // tail fill: [T*16, next 64-boundary past i0+7), clipped to this stage
    const int fs = T << 4;
    const int fe = (((i0 + 7) >> 6) + 1) << 6;
    const int slo = s << 10, shi = slo + 1024;
    const int lo = fs > slo ? fs : slo;
    const int hi = fe < shi ? fe : shi;
    for (int j2 = lo + lane; j2 < hi; j2 += 64) sm.scores[r][j2 - slo] = NEGV;
  };

  float sc[32];
#pragma unroll
  for (int u = 0; u < 32; u++) sc[u] = NEGV;
  float vmax = NEGV, s1 = 0.0f, s2 = 0.0f;

  phase1_stage(0);
  lds_barrier();
  LOAD_CHUNKS(0)
  if (i0 >= 1024) {                    // block-uniform: second half exists
    lds_barrier();                     // all waves done reading half 0
    phase1_stage(1);
    lds_barrier();
    LOAD_CHUNKS(16)
  }

  // ---- selection: stats reduction + probe-seeded exact bisection ----
#pragma unroll
  for (int off = 32; off; off >>= 1) {
    vmax = fmaxf(vmax, __shfl_xor(vmax, off));
    s1 += __shfl_xor(s1, off);
    s2 += __shfl_xor(s2, off);
  }

  auto countge = [&](float th) -> int {
    int cnt = 0;
#pragma unroll
    for (int u = 0; u < 32; u++)
      if ((u << 6) <= i)
        cnt += __popcll(__ballot(sc[u] >= th));
    return cnt;
  };

  float vk;
  if (i + 1 <= 64) {
    vk = NEGV;                         // <=64 valid: keep all
  } else {
    const float n1  = (float)(i + 1);
    const float mu  = s1 / n1;
    const float sig = sqrtf(fmaxf(s2 / n1 - mu * mu, 0.0f));
    // inverse-normal probe targeting count ~128 (Hastings approx)
    const float qf = fminf(0.45f, 128.0f / n1);
    const float tq = sqrtf(-2.0f * __logf(qf));
    const float zq = tq - (2.30753f + 0.27061f * tq) /
                          (1.0f + tq * (0.99229f + 0.04481f * tq));
    unsigned int ka, kb2;
    int ca, cb;
    {
      const float t1 = mu + zq * sig;
      const int c1 = countge(t1);
      if (c1 >= 64) { ka = f2k(t1); ca = c1; kb2 = f2k(vmax) + 1u; cb = 0; }
      else {
        const float t2 = mu + (zq - 0.85f) * sig;
        const int c2 = countge(t2);
        if (c2 >= 64) { ka = f2k(t2); ca = c2; kb2 = f2k(t1); cb = c1; }
        else { ka = f2k(-5000.0f); ca = i + 1; kb2 = f2k(t2); cb = c2; }
      }
    }
    int guard = 0;
    while (kb2 - ka > 1u && (ca - cb) > 56 && guard < 64) {
      guard++;
      float fm = 0.5f * (k2f(ka) + k2f(kb2));
      unsigned int km = f2k(fm);
      if (km <= ka || km >= kb2) km = ka + ((kb2 - ka) >> 1);
      const int cnt = countge(k2f(km));
      if (cnt >= 64) { ka = km; ca = cnt; } else { kb2 = km; cb = cnt; }
    }
    if (kb2 - ka == 1u || (ca - cb) > 64) {
      vk = k2f(ka);                    // interval collapsed (dups) -> exact
    } else {
      const float fka = k2f(ka), fkb = k2f(kb2);
      int cbase = 0;
#pragma unroll
      for (int u = 0; u < 32; u++) {
        if ((u << 6) <= i) {
          float kx = sc[u];
          bool in = (kx >= fka && kx < fkb);
          unsigned long long mask = __ballot(in);
          if (in) sm.cand[w][cbase + lanecnt_lt(mask)] = kx;
          cbase += __popcll(mask);
        }
      }
      const int nc = cbase;            // <= 64 on this path
      float cv = (lane < nc) ? sm.cand[w][lane] : -3.4e38f;
      for (int ks = 2; ks <= 64; ks <<= 1) {
        for (int j2 = ks >> 1; j2 > 0; j2 >>= 1) {
          float other = __shfl_xor(cv, j2);
          bool up    = ((lane & ks) == 0);
          bool lower = ((lane & j2) == 0);
          float mn = fminf(cv, other), mx = fmaxf(cv, other);
          cv = (up == lower) ? mn : mx;
        }
      }
      int need = 64 - cb;
      vk = __shfl(cv, 64 - need);
    }
  }

  // softmax + packed (p, j) kept list (scores pre-scaled by log2e -> exp2f)
  float z = 0.0f;
  int base = 0;
#pragma unroll
  for (int u = 0; u < 32; u++) {
    if ((u << 6) <= i) {
      const int j = (u << 6) + lane;
      float sv = sc[u];
      float p = (sv >= vk) ? exp2f(sv - vmax) : 0.0f;  // NEG entries -> exactly 0
      z += p;
      unsigned long long mask = __ballot(p > 0.0f);
      if (p > 0.0f) {
        int pos = base + lanecnt_lt(mask);
        if (pos < LIST_CAP) {
          float2 e; e.x = p; e.y = __uint_as_float((unsigned int)j);
          sm.pl[r][pos] = e;
        }
      }
      base += __popcll(mask);
    }
  }
#pragma unroll
  for (int off = 32; off; off >>= 1) z += __shfl_xor(z, off);
  const float rz = 1.0f / z;

  // ---- PV ----
  const float* vb2 = vbase + lane;
  float acc = 0.0f;
  if (base <= LIST_CAP) {
    // sparse: two-deep pipelined batches of 8. sc[] dead on this arm —
    // pipeline state reuses their registers (do not hoist out of this block).
    if (lane < 32) {                   // 32 zero-pads cover all refills:
      float2 e; e.x = 0.0f; e.y = __uint_as_float(0u);   // max idx = base+30
      sm.pl[r][base + lane] = e;
    }
    float2 curA[8], curB[8];
    float vvA[8], vvB[8];
#pragma unroll
    for (int s = 0; s < 8; s++) curA[s] = sm.pl[r][s];
#pragma unroll
    for (int s = 0; s < 8; s++) curB[s] = sm.pl[r][8 + s];
#pragma unroll
    for (int s = 0; s < 8; s++)
      vvA[s] = vb2[(size_t)(__float_as_uint(curA[s].y) << 6)];
#pragma unroll
    for (int s = 0; s < 8; s++)
      vvB[s] = vb2[(size_t)(__float_as_uint(curB[s].y) << 6)];

    const int nb2 = (base + 7) >> 3;
    for (int b = 0; b < nb2; b += 2) {
      // consume A (batch b), refill A with batch b+2
#pragma unroll
      for (int s = 0; s < 8; s++) acc = fmaf(curA[s].x, vvA[s], acc);
      const int ia = (b + 2) * 8;
#pragma unroll
      for (int s = 0; s < 8; s++) curA[s] = sm.pl[r][ia + s];
#pragma unroll
      for (int s = 0; s < 8; s++)
        vvA[s] = vb2[(size_t)(__float_as_uint(curA[s].y) << 6)];
      // consume B (batch b+1), refill B with batch b+3
#pragma unroll
      for (int s = 0; s < 8; s++) acc = fmaf(curB[s].x, vvB[s], acc);
      const int ib = (b + 3) * 8;
#pragma unroll
      for (int s = 0; s < 8; s++) curB[s] = sm.pl[r][ib + s];
#pragma unroll
      for (int s = 0; s < 8; s++)
        vvB[s] = vb2[(size_t)(__float_as_uint(curB[s].y) << 6)];
    }
  } else {                             // ties pathology: dense from registers
#pragma unroll
    for (int u = 0; u < 32; u++) {
      if ((u << 6) <= i) {
        float svu = sc[u];             // static index: sc stays in VGPRs
        for (int l2 = 0; l2 < 64; l2++) {
          const int jx = (u << 6) + l2;
          if (jx > i) break;
          float sv = __shfl(svu, l2);
          float p = (sv >= vk) ? exp2f(sv - vmax) : 0.0f;
          acc = fmaf(p, vb2[(size_t)((unsigned int)jx << 6)], acc);
        }
      }
    }
  }

  // epilogue: write ao as hl planes (row-major M x 2048) for the final GEMM
  const int bb = bh >> 4, hh = bh & 15;
  float val = acc * rz;
  unsigned short h, l;
  split_hl(val, &h, &l);
  const size_t arow = (size_t)(bb * SEQ + i) * 2048;
  aohl[arow + hh * 64 + lane] = h;
  aohl[arow + 1024 + hh * 64 + lane] = l;
}

// ---------------------------------------------------------------------------
extern "C" void kernel_launch(void* const* d_in, const int* in_sizes, int n_in,
                              void* d_out, int out_size, void* d_ws, size_t ws_size,
                              hipStream_t stream)
{
  const float* query = (const float*)d_in[0];
  const float* key   = (const float*)d_in[1];
  const float* value = (const float*)d_in[2];
  const float* Wq    = (const float*)d_in[3];
  const float* bq    = (const float*)d_in[4];
  const float* Wk    = (const float*)d_in[5];
  const float* bk    = (const float*)d_in[6];
  const float* Wv    = (const float*)d_in[7];
  const float* bv    = (const float*)d_in[8];
  const float* Wo    = (const float*)d_in[9];
  const float* bo    = (const float*)d_in[10];

  // ws (54.5 MB): xhl(16) | whl(4) | qhl(16) | khl(16). V fp32 lives in d_out
  // (scratch until the final GEMM overwrites it).
  unsigned short* xhl = (unsigned short*)d_ws;            // 4096 x 2048
  unsigned short* whl = xhl + (size_t)4096 * 2048;        // 1024 x 2048
  unsigned short* qhl = whl + (size_t)1024 * 2048;        // 65536 x 128 (bhsd hl)
  unsigned short* khl = qhl + (size_t)65536 * 128;
  float* vpf = (float*)d_out;                             // 65536 x 64 fp32 (bhsd)

  hipLaunchKernelGGL(conv_xhl, dim3(4096), dim3(256), 0, stream, query, xhl);
  hipLaunchKernelGGL(conv_whl, dim3(1024), dim3(256), 0, stream, Wq, whl);
  hipLaunchKernelGGL(gemm_mfma, dim3(512), dim3(256), 0, stream, xhl, whl, bq,
                     (float*)nullptr, qhl, (float*)nullptr, 1);
  hipLaunchKernelGGL(conv_xhl, dim3(4096), dim3(256), 0, stream, key, xhl);
  hipLaunchKernelGGL(conv_whl, dim3(1024), dim3(256), 0, stream, Wk, whl);
  hipLaunchKernelGGL(gemm_mfma, dim3(512), dim3(256), 0, stream, xhl, whl, bk,
                     (float*)nullptr, khl, (float*)nullptr, 1);
  hipLaunchKernelGGL(conv_xhl, dim3(4096), dim3(256), 0, stream, value, xhl);
  hipLaunchKernelGGL(conv_whl, dim3(1024), dim3(256), 0, stream, Wv, whl);
  hipLaunchKernelGGL(gemm_mfma, dim3(512), dim3(256), 0, stream, xhl, whl, bv,
                     (float*)nullptr, (unsigned short*)nullptr, vpf, 2);
  hipLaunchKernelGGL(attn_topk, dim3(8192), dim3(512), 0, stream, qhl, khl, vpf, xhl);
  hipLaunchKernelGGL(conv_whl, dim3(1024), dim3(256), 0, stream, Wo, whl);
  hipLaunchKernelGGL(gemm_mfma, dim3(512), dim3(256), 0, stream, xhl, whl, bo,
                     (float*)d_out, (unsigned short*)nullptr, (float*)nullptr, 0);
}